// Round 5
// baseline (1152.707 us; speedup 1.0000x reference)
//
#include <hip/hip_runtime.h>
#include <stdint.h>

// ---------------- constants ----------------
#define NN    2048          // nodes
#define BB    16            // batch
#define CC    64            // in channels
#define TT    12            // time
#define OO    64            // out channels
#define ED    10            // embed dim
#define JJ    12288         // B*T*C  (j = (b*T+t)*C + c)
#define NJ    25165824      // NN*JJ
#define KC    192           // 3*C contraction of per-node GEMM
#define NTK   32            // K-tiles in the big GEMM (2048 / 64)

typedef __attribute__((ext_vector_type(8))) short short8;   // 8 bf16 = 4 VGPR
typedef __attribute__((ext_vector_type(4))) float f32x4;

__device__ __forceinline__ unsigned short f2bf(float x) {
    union { float f; unsigned int u; } v; v.f = x;
    unsigned int r = (v.u + 0x7FFFu + ((v.u >> 16) & 1u)) >> 16;
    return (unsigned short)r;
}
__device__ __forceinline__ float bf2f(unsigned short h) {
    union { unsigned int u; float f; } v; v.u = ((unsigned int)h) << 16;
    return v.f;
}
__device__ __forceinline__ void async_cp16(const void* g, void* l) {
    __builtin_amdgcn_global_load_lds(
        (const __attribute__((address_space(1))) void*)(uintptr_t)g,
        (__attribute__((address_space(3))) void*)(uintptr_t)l, 16, 0, 0);
}

// ---------------- K1: A = softmax(relu(E E^T)) row-wise -> bf16 ----------------
__global__ __launch_bounds__(256) void k_softmax_A(const float* __restrict__ E,
                                                   unsigned short* __restrict__ Abf) {
    int n = blockIdx.x, tid = threadIdx.x;
    __shared__ float row[NN];
    __shared__ float red[256];
    float en[ED];
#pragma unroll
    for (int d = 0; d < ED; ++d) en[d] = E[n * ED + d];
    float mx = 0.0f;  // relu => values >= 0
    for (int m = tid; m < NN; m += 256) {
        float s = 0.f;
#pragma unroll
        for (int d = 0; d < ED; ++d) s += en[d] * E[m * ED + d];
        s = fmaxf(s, 0.0f);
        row[m] = s;
        mx = fmaxf(mx, s);
    }
    red[tid] = mx; __syncthreads();
    for (int s = 128; s; s >>= 1) { if (tid < s) red[tid] = fmaxf(red[tid], red[tid + s]); __syncthreads(); }
    mx = red[0]; __syncthreads();
    float sum = 0.f;
    for (int m = tid; m < NN; m += 256) { float e = __expf(row[m] - mx); row[m] = e; sum += e; }
    red[tid] = sum; __syncthreads();
    for (int s = 128; s; s >>= 1) { if (tid < s) red[tid] += red[tid + s]; __syncthreads(); }
    float inv = 1.0f / red[0];
    for (int m = tid; m < NN; m += 256) Abf[(size_t)n * NN + m] = f2bf(row[m] * inv);
}

// ---------------- K2: At[w][v] = support[v][w] -> bf16 ----------------
__global__ void k_trans_bf(const float* __restrict__ src, unsigned short* __restrict__ dst) {
    __shared__ float t[32][33];
    int tx = threadIdx.x, ty = threadIdx.y;     // (32, 8)
    int x0 = blockIdx.x * 32, y0 = blockIdx.y * 32;
#pragma unroll
    for (int i = 0; i < 4; ++i)
        t[ty + i * 8][tx] = src[(size_t)(y0 + ty + i * 8) * NN + x0 + tx];
    __syncthreads();
#pragma unroll
    for (int i = 0; i < 4; ++i)
        dst[(size_t)(x0 + ty + i * 8) * NN + y0 + tx] = f2bf(t[tx][ty + i * 8]);
}

// ---------------- K3: fused X2 + X2t builder (coalesced both sides) ----------------
// Block = (b, n-tile of 32).  Reads x[b][c][n0..n0+31][t] as 64 contiguous
// 1.5 KB segments (float4), stages in LDS [c][n][t] with strides 417/13
// (bank-conflict-free for both c-major and n-major access), then writes:
//   X2 [n][b*768 + t*64 + c]   (16B chunks, row-contiguous)
//   X2t[(b*768+j)][n0 + n]     (16B chunks along n, 64B segments)
// Replaces the scatter-read k_make_X2 (4B/lane @ 98KB stride) + one k_trans16.
__global__ __launch_bounds__(256) void k_make_X2b(const float* __restrict__ x,
                                                  unsigned short* __restrict__ X2,
                                                  unsigned short* __restrict__ X2t) {
    extern __shared__ float lx[];            // 64*417 floats = 104.25 KB
    int b = blockIdx.x, n0 = blockIdx.y * 32, tid = threadIdx.x;
    // read-in: 6144 float4 = 24/thread
#pragma unroll
    for (int v = 0; v < 24; ++v) {
        int f4 = v * 256 + tid;
        int c = f4 / 96, r4 = f4 - c * 96;
        const float4* src = (const float4*)(x + ((size_t)(b * CC + c) * NN + n0) * TT) + r4;
        float4 val = *src;
#pragma unroll
        for (int u = 0; u < 4; ++u) {
            int idx = r4 * 4 + u;
            int n = idx / 12, t = idx - n * 12;
            lx[c * 417 + n * 13 + t] = ((const float*)&val)[u];
        }
    }
    __syncthreads();
    // X2: 32 rows x 768 j, short8 runs (c varies within run, bank stride 417%32=1)
#pragma unroll
    for (int v = 0; v < 12; ++v) {
        int flat = v * 256 + tid;            // 3072 runs
        int n = flat / 96, u8 = flat - n * 96;
        int jl = u8 * 8;
        int t = jl >> 6, c0 = jl & 63;
        unsigned short w[8];
#pragma unroll
        for (int e = 0; e < 8; ++e) w[e] = f2bf(lx[(c0 + e) * 417 + n * 13 + t]);
        *(short8*)&X2[(size_t)(n0 + n) * JJ + b * 768 + jl] = *(short8*)w;
    }
    // X2t: 768 j x 32 n, short8 runs along n (bank stride 13)
#pragma unroll
    for (int v = 0; v < 12; ++v) {
        int flat = v * 256 + tid;
        int jl = flat >> 2, nq = (flat & 3) * 8;
        int t = jl >> 6, c = jl & 63;
        unsigned short w[8];
#pragma unroll
        for (int e = 0; e < 8; ++e) w[e] = f2bf(lx[c * 417 + (nq + e) * 13 + t]);
        *(short8*)&X2t[(size_t)(b * 768 + jl) * NN + n0 + nq] = *(short8*)w;
    }
}

// ---------------- K3b: bf16 tiled transpose  dst[j][n] = src[n][j] ----------------
__global__ __launch_bounds__(256) void k_trans16(const unsigned short* __restrict__ src,
                                                 unsigned short* __restrict__ dst) {
    __shared__ unsigned short t[64][72];     // pad 72 shorts
    int tid = threadIdx.x;
    int j0 = blockIdx.x * 64, n0 = blockIdx.y * 64;
    int r = tid >> 3, c8 = (tid & 7) * 8;    // 32 rows per pass, 8 shorts per thread
#pragma unroll
    for (int it = 0; it < 2; ++it) {
        int rr = r + it * 32;
        *(short8*)&t[rr][c8] = *(const short8*)&src[(size_t)(n0 + rr) * JJ + j0 + c8];
    }
    __syncthreads();
#pragma unroll
    for (int it = 0; it < 2; ++it) {
        int rr = r + it * 32;                // j-row within tile
        unsigned short v[8];
#pragma unroll
        for (int u = 0; u < 8; ++u) v[u] = t[c8 + u][rr];
        *(short8*)&dst[(size_t)(j0 + rr) * NN + n0 + c8] = *(short8*)v;
    }
}

// ---------------- K4: 256x256 bf16 MFMA GEMM (z-mergeable) ----------------
// Out[m][j] = sum_k Am[m][k] * Bt[j][k]; blockIdx.z selects (Am,Out) pair so
// independent GEMMs sharing B merge into a 768-block dispatch (3 exact rounds;
// measured R4: full-round merged runs at ~1.1 PF effective per-block vs ~775 TF
// in 1.5-round singles). Csub path removed: the Chebyshev "2*A*Y1 - X2" is
// folded into k_node's weights ((W0-W2), W1, 2*W2) so ALL big GEMMs are plain.
template <int AOFF, int BOFF>
__device__ __forceinline__ void mfma_quad(f32x4 (&acc)[8][4],
                                          const short8 (&A)[4][2],
                                          const short8 (&B)[2][2]) {
    __builtin_amdgcn_s_setprio(1);
#pragma unroll
    for (int h = 0; h < 2; ++h)          // h outermost: 8 independent accs between deps
#pragma unroll
        for (int tm = 0; tm < 4; ++tm)
#pragma unroll
            for (int tn = 0; tn < 2; ++tn)
                acc[AOFF + tm][BOFF + tn] = __builtin_amdgcn_mfma_f32_16x16x32_bf16(
                    A[tm][h], B[tn][h], acc[AOFF + tm][BOFF + tn], 0, 0, 0);
    __builtin_amdgcn_s_setprio(0);
}

__global__ __launch_bounds__(512, 2) void k_gemm8(const unsigned short* __restrict__ AmA,
                                                  const unsigned short* __restrict__ AmB,
                                                  const unsigned short* __restrict__ Bt,
                                                  unsigned short* __restrict__ OutA,
                                                  unsigned short* __restrict__ OutB) {
    extern __shared__ char ldsc[];   // [buf:2][A 32KB | B 32KB] = 128 KiB
    int tid = threadIdx.x, lane = tid & 63, wv = tid >> 6;
    int q = lane >> 4, l15 = lane & 15;

    const unsigned short* Am = blockIdx.z ? AmB : AmA;
    unsigned short* Out      = blockIdx.z ? OutB : OutA;

    int j0g = blockIdx.x * 256, m0g = blockIdx.y * 256;   // natural order

    int wmw = (wv >> 2) * 128;       // wave m offset in tile
    int wnw = (wv & 3) * 64;         // wave j offset in tile

    // ---- staging bases: inverse-swizzled global source, linear LDS dest ----
    int srow = tid >> 3;                                   // row within half-tile (0..63)
    int scol = ((tid & 7) * 16) ^ ((srow & 7) << 4);       // swizzled byte col in k-row
    const char* srcA0 = (const char*)Am + (size_t)(m0g + srow) * 4096 + scol;
    const char* srcB0 = (const char*)Bt + (size_t)(j0g + srow) * 4096 + scol;
    char* dstA0 = ldsc + tid * 16;
    char* dstB0 = ldsc + 32768 + tid * 16;

// half-tile = 128 rows x 128 B = 16 KiB = 2 loads/thread (rows +0 / +64)
#define STAGE_A(nb, kt, h)                                                                  \
    do {                                                                                    \
        async_cp16(srcA0 + (size_t)(kt) * 128 + (h) * 524288,                               \
                   dstA0 + (nb) * 65536 + (h) * 16384);                                     \
        async_cp16(srcA0 + (size_t)(kt) * 128 + (h) * 524288 + 262144,                      \
                   dstA0 + (nb) * 65536 + (h) * 16384 + 8192);                              \
    } while (0)
#define STAGE_B(nb, kt, h)                                                                  \
    do {                                                                                    \
        async_cp16(srcB0 + (size_t)(kt) * 128 + (h) * 524288,                               \
                   dstB0 + (nb) * 65536 + (h) * 16384);                                     \
        async_cp16(srcB0 + (size_t)(kt) * 128 + (h) * 524288 + 262144,                      \
                   dstB0 + (nb) * 65536 + (h) * 16384 + 8192);                              \
    } while (0)

    // ---- read-side swizzled column offsets (per lane, constant all tiles) ----
    int rsw = (l15 & 7) << 4;                 // row&7 == l15&7 for every fragment row
    int colh0 = (q * 16) ^ rsw;               // k-half 0
    int colh1 = colh0 ^ 64;                   // k-half 1 (bit 6 flips cleanly under XOR)
    int arA = (wmw + l15) * 128;
    int arB = (wnw + l15) * 128;

    f32x4 acc[8][4];
#pragma unroll
    for (int a = 0; a < 8; ++a)
#pragma unroll
        for (int b = 0; b < 4; ++b) acc[a][b] = (f32x4){0.f, 0.f, 0.f, 0.f};

    // ---- prologue: tile0 {A,B} -> buf0 (8 loads); t1.B -> buf1 (4 loads) ----
    STAGE_A(0, 0, 0);
    STAGE_A(0, 0, 1);
    STAGE_B(0, 0, 0);
    STAGE_B(0, 0, 1);
    STAGE_B(1, 1, 0);
    STAGE_B(1, 1, 1);
    asm volatile("s_waitcnt vmcnt(4)" ::: "memory");   // tile0 landed; t1.B in flight
    __builtin_amdgcn_s_barrier();
    asm volatile("" ::: "memory");

    int cur = 0;
    for (int t = 0; t < NTK; ++t, cur ^= 1) {
        const int nb = cur ^ 1;
        const char* pa = ldsc + (cur << 16);
        const char* pA0 = pa + arA;
        const char* pB0 = pa + 32768 + arB;

        // ---- top: stage (t+1).A into other buffer (no hazard: nb not read now) ----
        if (t + 1 < NTK) {
            STAGE_A(nb, t + 1, 0);
            STAGE_A(nb, t + 1, 1);
        }

        short8 af[4][2], bf0[2][2], bf1[2][2];

        // ---- first half: read A[m0] + all B, MFMA 2 quads (no barrier inside) ----
#pragma unroll
        for (int tm = 0; tm < 4; ++tm) {
            af[tm][0] = *(const short8*)(pA0 + tm * 2048 + colh0);
            af[tm][1] = *(const short8*)(pA0 + tm * 2048 + colh1);
        }
#pragma unroll
        for (int tn = 0; tn < 2; ++tn) {
            bf0[tn][0] = *(const short8*)(pB0 + tn * 2048 + colh0);
            bf0[tn][1] = *(const short8*)(pB0 + tn * 2048 + colh1);
            bf1[tn][0] = *(const short8*)(pB0 + 4096 + tn * 2048 + colh0);
            bf1[tn][1] = *(const short8*)(pB0 + 4096 + tn * 2048 + colh1);
        }
        mfma_quad<0, 0>(acc, af, bf0);
        mfma_quad<0, 2>(acc, af, bf1);

        // ---- hazard #1: B reads complete -> overwrite cur B with (t+2).B ----
        if (t + 2 < NTK) {
            asm volatile("s_waitcnt lgkmcnt(0)" ::: "memory");
            __builtin_amdgcn_s_barrier();
            asm volatile("" ::: "memory");
            STAGE_B(cur, t + 2, 0);
            STAGE_B(cur, t + 2, 1);
        }

        // ---- second half: read A[m1], MFMA 2 quads (no barrier inside) ----
#pragma unroll
        for (int tm = 0; tm < 4; ++tm) {
            af[tm][0] = *(const short8*)(pA0 + 8192 + tm * 2048 + colh0);
            af[tm][1] = *(const short8*)(pA0 + 8192 + tm * 2048 + colh1);
        }
        mfma_quad<4, 2>(acc, af, bf1);
        mfma_quad<4, 0>(acc, af, bf0);

        // ---- hazard #2 (boundary): all reads done; (t+1) landed; B(t+2) in flight ----
        if (t + 2 < NTK) {
            asm volatile("s_waitcnt vmcnt(4) lgkmcnt(0)" ::: "memory");
            __builtin_amdgcn_s_barrier();
            asm volatile("" ::: "memory");
        } else if (t + 1 < NTK) {
            asm volatile("s_waitcnt vmcnt(0) lgkmcnt(0)" ::: "memory");
            __builtin_amdgcn_s_barrier();
            asm volatile("" ::: "memory");
        }
        // t == NTK-1: fall through to epilogue (registers only)
    }
#undef STAGE_A
#undef STAGE_B

    // ---- epilogue: Out[m][j] bf16 ----
#pragma unroll
    for (int a = 0; a < 8; ++a) {
        int mbase = m0g + wmw + (a >> 2) * 64 + (a & 3) * 16 + q * 4;
#pragma unroll
        for (int b = 0; b < 4; ++b) {
            int jj = j0g + wnw + (b >> 1) * 32 + (b & 1) * 16 + l15;
#pragma unroll
            for (int r = 0; r < 4; ++r) {
                size_t oidx = (size_t)(mbase + r) * JJ + jj;
                Out[oidx] = f2bf(acc[a][b][r]);
            }
        }
    }
}

// ---------------- K5/K6: per-node [192 x 192] @ [192 x 64] MFMA GEMM ----------------
// branch 0 (adaptive): sources (X2, Y1, Y2'=A*Y1) with FOLDED weights
//   (W0-W2, W1, 2*W2): equals W0*X2 + W1*Y1 + W2*(2*A*Y1 - X2) = reference.
// branch 1 (diffusion): sources (X2, Z1, Z2), plain weights.
__global__ __launch_bounds__(256) void k_node(const unsigned short* __restrict__ S0,
                                              const unsigned short* __restrict__ S1,
                                              const unsigned short* __restrict__ S2,
                                              const float* __restrict__ E,
                                              const float* __restrict__ Wp,
                                              const float* __restrict__ bias_pool,
                                              const float* __restrict__ mlp_w,
                                              const float* __restrict__ mlp_b,
                                              float* __restrict__ out,
                                              int branch) {
    int n = blockIdx.x, tid = threadIdx.x, lane = tid & 63, wv = tid >> 6;
    __shared__ __align__(16) unsigned short lW[64 * 200];   // W^T: [o][kappa] pad->200
    __shared__ __align__(16) unsigned short lS[192 * 72];   // one source: [m][i] pad->72
    __shared__ float lBias[64];
    int q = lane >> 4, l15 = lane & 15;

    if (branch == 0) {
        float en[ED];
#pragma unroll
        for (int d = 0; d < ED; ++d) en[d] = E[n * ED + d];
        for (int idx = tid; idx < KC * OO; idx += 256) {
            int o = idx & 63, kap = idx >> 6;                  // kap = k*64+i
            int k = kap >> 6, i = kap & 63;
            float s = 0.f;
#pragma unroll
            for (int d = 0; d < ED; ++d) {
                float w;
                if (k == 0)
                    w = Wp[((size_t)d * KC + i) * OO + o] - Wp[((size_t)d * KC + 128 + i) * OO + o];
                else if (k == 1)
                    w = Wp[((size_t)d * KC + 64 + i) * OO + o];
                else
                    w = 2.0f * Wp[((size_t)d * KC + 128 + i) * OO + o];
                s += en[d] * w;
            }
            lW[o * 200 + kap] = f2bf(s);
        }
        if (tid < 64) {
            float s = 0.f;
#pragma unroll
            for (int d = 0; d < ED; ++d) s += en[d] * bias_pool[d * OO + tid];
            lBias[tid] = s;
        }
    } else {
        for (int idx = tid; idx < KC * OO; idx += 256) {
            int o = idx & 63, kap = idx >> 6;
            lW[o * 200 + kap] = f2bf(mlp_w[kap * OO + o]);
        }
        if (tid < 64) lBias[tid] = mlp_b[tid];
    }

    f32x4 zero = {0.f, 0.f, 0.f, 0.f};
    f32x4 acc[3][4];
#pragma unroll
    for (int a = 0; a < 3; ++a)
#pragma unroll
        for (int b = 0; b < 4; ++b) acc[a][b] = zero;

    const unsigned short* Ss[3] = { S0 + (size_t)n * JJ, S1 + (size_t)n * JJ, S2 + (size_t)n * JJ };

    for (int s = 0; s < 3; ++s) {
        __syncthreads();
        // stage source row: 12288 bf16 -> lS[m][i] (pad 72)
#pragma unroll
        for (int v = 0; v < 6; ++v) {
            int e8 = (v * 256 + tid) * 8;
            int m = e8 >> 6, i = e8 & 63;
            *(short8*)&lS[m * 72 + i] = *(const short8*)&Ss[s][e8];
        }
        __syncthreads();
#pragma unroll
        for (int h = 0; h < 2; ++h) {
            short8 af[3], bfr[4];
#pragma unroll
            for (int tm = 0; tm < 3; ++tm)
                af[tm] = *(const short8*)&lS[(wv * 48 + tm * 16 + l15) * 72 + h * 32 + q * 8];
#pragma unroll
            for (int tn = 0; tn < 4; ++tn)
                bfr[tn] = *(const short8*)&lW[(tn * 16 + l15) * 200 + s * 64 + h * 32 + q * 8];
#pragma unroll
            for (int tm = 0; tm < 3; ++tm)
#pragma unroll
                for (int tn = 0; tn < 4; ++tn)
                    acc[tm][tn] = __builtin_amdgcn_mfma_f32_16x16x32_bf16(af[tm], bfr[tn], acc[tm][tn], 0, 0, 0);
        }
    }
    // epilogue: out[b][o][n][t] fp32, m = b*T+t
#pragma unroll
    for (int tm = 0; tm < 3; ++tm) {
#pragma unroll
        for (int tn = 0; tn < 4; ++tn) {
            int o = tn * 16 + l15;
#pragma unroll
            for (int r = 0; r < 4; ++r) {
                int m = wv * 48 + tm * 16 + q * 4 + r;
                int b = m / TT, t = m - b * TT;
                out[(((size_t)b * OO + o) * NN + n) * TT + t] = acc[tm][tn][r] + lBias[o];
            }
        }
    }
}

// ---------------- launch ----------------
extern "C" void kernel_launch(void* const* d_in, const int* in_sizes, int n_in,
                              void* d_out, int out_size, void* d_ws, size_t ws_size,
                              hipStream_t stream) {
    const float* x         = (const float*)d_in[0];
    const float* node_emb  = (const float*)d_in[1];
    const float* support   = (const float*)d_in[2];
    const float* wpool     = (const float*)d_in[3];
    const float* bpool     = (const float*)d_in[4];
    const float* mlp_w     = (const float*)d_in[5];
    const float* mlp_b     = (const float*)d_in[6];
    float* out             = (float*)d_out;

    // workspace map (256 MB exactly):
    unsigned short* Abf = (unsigned short*)d_ws;                 // 8 MB
    unsigned short* Atb = Abf + (size_t)NN * NN;                 // 8 MB
    unsigned short* b1  = Atb + (size_t)NN * NN;                 // X2t, later Y2'
    unsigned short* b2  = b1 + (size_t)NJ;                       // X2
    unsigned short* b3  = b2 + (size_t)NJ;                       // Y1t, later Z1t
    unsigned short* b4  = b3 + (size_t)NJ;                       // Y1, later Z2
    unsigned short* b5  = b4 + (size_t)NJ;                       // Z1
    // liveness:
    //   make  : X2 -> b2, X2t -> b1
    //   G13   : Y1 -> b4, Z1 -> b5          (B = X2t = b1)
    //   T1    : b4 -> b3 (Y1t)
    //   G2    : Y2' = A*Y1t -> b1           (X2t dead; weight-fold, no Csub)
    //   node0 : (b2, b4, b1) folded weights
    //   T2    : b5 -> b3 (Z1t)
    //   G4    : Z2 = At*Z1t -> b4           (Y1 dead)
    //   node1 : (b2, b5, b4) plain weights

    static int attr_done = 0;
    if (!attr_done) {
        hipFuncSetAttribute(reinterpret_cast<const void*>(k_gemm8),
                            hipFuncAttributeMaxDynamicSharedMemorySize, 131072);
        hipFuncSetAttribute(reinterpret_cast<const void*>(k_make_X2b),
                            hipFuncAttributeMaxDynamicSharedMemorySize, 106752);
        attr_done = 1;
    }

    dim3 gg13(48, 8, 2);             // merged Y1/Z1 dispatch: 768 blocks = 3 rounds
    dim3 gg1(48, 8, 1);              // single GEMM
    dim3 gt(192, 32);                // transpose grid (64x64 tiles)

    // prep
    k_softmax_A<<<NN, 256, 0, stream>>>(node_emb, Abf);
    k_trans_bf<<<dim3(64, 64), dim3(32, 8), 0, stream>>>(support, Atb);
    k_make_X2b<<<dim3(16, 64), 256, 106752, stream>>>(x, b2, b1);   // X2 + X2t fused

    // merged: Y1 = A*X2 (z=0), Z1 = At*X2 (z=1)
    k_gemm8<<<gg13, 512, 131072, stream>>>(Abf, Atb, b1, b4, b5);

    // adaptive branch tail
    k_trans16<<<gt, 256, 0, stream>>>(b4, b3);                      // Y1t
    k_gemm8<<<gg1, 512, 131072, stream>>>(Abf, Abf, b3, b1, b1);    // Y2' -> b1
    k_node<<<NN, 256, 0, stream>>>(b2, b4, b1, node_emb, wpool, bpool, nullptr, nullptr,
                                   out, 0);

    // diffusion branch tail
    k_trans16<<<gt, 256, 0, stream>>>(b5, b3);                      // Z1t
    k_gemm8<<<gg1, 512, 131072, stream>>>(Atb, Atb, b3, b4, b4);    // Z2 -> b4
    k_node<<<NN, 256, 0, stream>>>(b2, b5, b4, nullptr, nullptr, nullptr, mlp_w, mlp_b,
                                   out + (size_t)NJ, 1);
}

// Round 6
// 966.264 us; speedup vs baseline: 1.1930x; 1.1930x over previous
//
#include <hip/hip_runtime.h>
#include <stdint.h>

// ---------------- constants ----------------
#define NN    2048          // nodes
#define BB    16            // batch
#define CC    64            // in channels
#define TT    12            // time
#define OO    64            // out channels
#define ED    10            // embed dim
#define JJ    12288         // B*T*C  (j = (b*T+t)*C + c)
#define NJ    25165824      // NN*JJ
#define KC    192           // 3*C contraction of per-node GEMM
#define NTK   32            // K-tiles in the big GEMM (2048 / 64)

typedef __attribute__((ext_vector_type(8))) short short8;   // 8 bf16 = 4 VGPR
typedef __attribute__((ext_vector_type(4))) float f32x4;

__device__ __forceinline__ unsigned short f2bf(float x) {
    union { float f; unsigned int u; } v; v.f = x;
    unsigned int r = (v.u + 0x7FFFu + ((v.u >> 16) & 1u)) >> 16;
    return (unsigned short)r;
}
__device__ __forceinline__ void async_cp16(const void* g, void* l) {
    __builtin_amdgcn_global_load_lds(
        (const __attribute__((address_space(1))) void*)(uintptr_t)g,
        (__attribute__((address_space(3))) void*)(uintptr_t)l, 16, 0, 0);
}

// ---------------- K1: A = softmax(relu(E E^T)) row-wise -> bf16 ----------------
__global__ __launch_bounds__(256) void k_softmax_A(const float* __restrict__ E,
                                                   unsigned short* __restrict__ Abf) {
    int n = blockIdx.x, tid = threadIdx.x;
    __shared__ float row[NN];
    __shared__ float red[256];
    float en[ED];
#pragma unroll
    for (int d = 0; d < ED; ++d) en[d] = E[n * ED + d];
    float mx = 0.0f;  // relu => values >= 0
    for (int m = tid; m < NN; m += 256) {
        float s = 0.f;
#pragma unroll
        for (int d = 0; d < ED; ++d) s += en[d] * E[m * ED + d];
        s = fmaxf(s, 0.0f);
        row[m] = s;
        mx = fmaxf(mx, s);
    }
    red[tid] = mx; __syncthreads();
    for (int s = 128; s; s >>= 1) { if (tid < s) red[tid] = fmaxf(red[tid], red[tid + s]); __syncthreads(); }
    mx = red[0]; __syncthreads();
    float sum = 0.f;
    for (int m = tid; m < NN; m += 256) { float e = __expf(row[m] - mx); row[m] = e; sum += e; }
    red[tid] = sum; __syncthreads();
    for (int s = 128; s; s >>= 1) { if (tid < s) red[tid] += red[tid + s]; __syncthreads(); }
    float inv = 1.0f / red[0];
    for (int m = tid; m < NN; m += 256) Abf[(size_t)n * NN + m] = f2bf(row[m] * inv);
}

// ---------------- K2: At[w][v] = support[v][w] -> bf16 ----------------
__global__ void k_trans_bf(const float* __restrict__ src, unsigned short* __restrict__ dst) {
    __shared__ float t[32][33];
    int tx = threadIdx.x, ty = threadIdx.y;     // (32, 8)
    int x0 = blockIdx.x * 32, y0 = blockIdx.y * 32;
#pragma unroll
    for (int i = 0; i < 4; ++i)
        t[ty + i * 8][tx] = src[(size_t)(y0 + ty + i * 8) * NN + x0 + tx];
    __syncthreads();
#pragma unroll
    for (int i = 0; i < 4; ++i)
        dst[(size_t)(x0 + ty + i * 8) * NN + y0 + tx] = f2bf(t[tx][ty + i * 8]);
}

// ---------------- K3: fused X2 + X2t builder (coalesced both sides) ----------------
__global__ __launch_bounds__(256) void k_make_X2b(const float* __restrict__ x,
                                                  unsigned short* __restrict__ X2,
                                                  unsigned short* __restrict__ X2t) {
    extern __shared__ float lx[];            // 64*417 floats = 104.25 KB
    int b = blockIdx.x, n0 = blockIdx.y * 32, tid = threadIdx.x;
#pragma unroll
    for (int v = 0; v < 24; ++v) {
        int f4 = v * 256 + tid;
        int c = f4 / 96, r4 = f4 - c * 96;
        const float4* src = (const float4*)(x + ((size_t)(b * CC + c) * NN + n0) * TT) + r4;
        float4 val = *src;
#pragma unroll
        for (int u = 0; u < 4; ++u) {
            int idx = r4 * 4 + u;
            int n = idx / 12, t = idx - n * 12;
            lx[c * 417 + n * 13 + t] = ((const float*)&val)[u];
        }
    }
    __syncthreads();
#pragma unroll
    for (int v = 0; v < 12; ++v) {
        int flat = v * 256 + tid;            // 3072 runs
        int n = flat / 96, u8 = flat - n * 96;
        int jl = u8 * 8;
        int t = jl >> 6, c0 = jl & 63;
        unsigned short w[8];
#pragma unroll
        for (int e = 0; e < 8; ++e) w[e] = f2bf(lx[(c0 + e) * 417 + n * 13 + t]);
        *(short8*)&X2[(size_t)(n0 + n) * JJ + b * 768 + jl] = *(short8*)w;
    }
#pragma unroll
    for (int v = 0; v < 12; ++v) {
        int flat = v * 256 + tid;
        int jl = flat >> 2, nq = (flat & 3) * 8;
        int t = jl >> 6, c = jl & 63;
        unsigned short w[8];
#pragma unroll
        for (int e = 0; e < 8; ++e) w[e] = f2bf(lx[c * 417 + (nq + e) * 13 + t]);
        *(short8*)&X2t[(size_t)(b * 768 + jl) * NN + n0 + nq] = *(short8*)w;
    }
}

// ---------------- K3b: bf16 tiled transpose  dst[j][n] = src[n][j] ----------------
__global__ __launch_bounds__(256) void k_trans16(const unsigned short* __restrict__ src,
                                                 unsigned short* __restrict__ dst) {
    __shared__ unsigned short t[64][72];     // pad 72 shorts
    int tid = threadIdx.x;
    int j0 = blockIdx.x * 64, n0 = blockIdx.y * 64;
    int r = tid >> 3, c8 = (tid & 7) * 8;
#pragma unroll
    for (int it = 0; it < 2; ++it) {
        int rr = r + it * 32;
        *(short8*)&t[rr][c8] = *(const short8*)&src[(size_t)(n0 + rr) * JJ + j0 + c8];
    }
    __syncthreads();
#pragma unroll
    for (int it = 0; it < 2; ++it) {
        int rr = r + it * 32;
        unsigned short v[8];
#pragma unroll
        for (int u = 0; u < 8; ++u) v[u] = t[c8 + u][rr];
        *(short8*)&dst[(size_t)(j0 + rr) * NN + n0 + c8] = *(short8*)v;
    }
}

// ---------------- K-wfold: W_all[n][o*192+kap] = sum_d E[n,d] * foldedWp[d,kap,o] ----------------
// fold: k=0 -> W0-W2, k=1 -> W1, k=2 -> 2*W2  (Chebyshev Y2 = 2*A*Y1 - X2 folded
// into the per-node weights so the big GEMMs never need a Csub stream).
// Replaces a per-block 491 KB Wp rescan in k_node (2048x redundant, ~1.5 GB L2).
__global__ __launch_bounds__(256) void k_wfold(const float* __restrict__ E,
                                               const float* __restrict__ Wp,
                                               unsigned short* __restrict__ Wall) {
    __shared__ float lE[256 * ED];           // 10 KB E slice
    int tid = threadIdx.x;
    int col = blockIdx.x * 256 + tid;        // [0,12288): col = o*192 + kap
    int o = col / 192, kap = col - o * 192;
    int n0 = blockIdx.y * 256;
#pragma unroll
    for (int v = 0; v < 10; ++v) lE[v * 256 + tid] = E[(size_t)n0 * ED + v * 256 + tid];
    int k = kap >> 6, i = kap & 63;
    float w[ED];
#pragma unroll
    for (int d = 0; d < ED; ++d) {
        float v;
        if (k == 0)
            v = Wp[((size_t)d * KC + i) * OO + o] - Wp[((size_t)d * KC + 128 + i) * OO + o];
        else if (k == 1)
            v = Wp[((size_t)d * KC + 64 + i) * OO + o];
        else
            v = 2.0f * Wp[((size_t)d * KC + 128 + i) * OO + o];
        w[d] = v;
    }
    __syncthreads();
    for (int nn = 0; nn < 256; ++nn) {
        float s = 0.f;
#pragma unroll
        for (int d = 0; d < ED; ++d) s += lE[nn * ED + d] * w[d];
        Wall[(size_t)(n0 + nn) * 12288 + col] = f2bf(s);   // wave = 128 B contiguous
    }
}

// ---------------- K4: 256x256 bf16 MFMA GEMM (z-mergeable, TAG = call site) ----------------
template <int AOFF, int BOFF>
__device__ __forceinline__ void mfma_quad(f32x4 (&acc)[8][4],
                                          const short8 (&A)[4][2],
                                          const short8 (&B)[2][2]) {
    __builtin_amdgcn_s_setprio(1);
#pragma unroll
    for (int h = 0; h < 2; ++h)
#pragma unroll
        for (int tm = 0; tm < 4; ++tm)
#pragma unroll
            for (int tn = 0; tn < 2; ++tn)
                acc[AOFF + tm][BOFF + tn] = __builtin_amdgcn_mfma_f32_16x16x32_bf16(
                    A[tm][h], B[tn][h], acc[AOFF + tm][BOFF + tn], 0, 0, 0);
    __builtin_amdgcn_s_setprio(0);
}

template <int TAG>
__global__ __launch_bounds__(512, 2) void k_gemm8(const unsigned short* __restrict__ AmA,
                                                  const unsigned short* __restrict__ AmB,
                                                  const unsigned short* __restrict__ Bt,
                                                  unsigned short* __restrict__ OutA,
                                                  unsigned short* __restrict__ OutB) {
    extern __shared__ char ldsc[];   // [buf:2][A 32KB | B 32KB] = 128 KiB
    int tid = threadIdx.x, lane = tid & 63, wv = tid >> 6;
    int q = lane >> 4, l15 = lane & 15;

    const unsigned short* Am = blockIdx.z ? AmB : AmA;
    unsigned short* Out      = blockIdx.z ? OutB : OutA;

    int j0g = blockIdx.x * 256, m0g = blockIdx.y * 256;

    int wmw = (wv >> 2) * 128;
    int wnw = (wv & 3) * 64;

    int srow = tid >> 3;
    int scol = ((tid & 7) * 16) ^ ((srow & 7) << 4);
    const char* srcA0 = (const char*)Am + (size_t)(m0g + srow) * 4096 + scol;
    const char* srcB0 = (const char*)Bt + (size_t)(j0g + srow) * 4096 + scol;
    char* dstA0 = ldsc + tid * 16;
    char* dstB0 = ldsc + 32768 + tid * 16;

#define STAGE_A(nb, kt, h)                                                                  \
    do {                                                                                    \
        async_cp16(srcA0 + (size_t)(kt) * 128 + (h) * 524288,                               \
                   dstA0 + (nb) * 65536 + (h) * 16384);                                     \
        async_cp16(srcA0 + (size_t)(kt) * 128 + (h) * 524288 + 262144,                      \
                   dstA0 + (nb) * 65536 + (h) * 16384 + 8192);                              \
    } while (0)
#define STAGE_B(nb, kt, h)                                                                  \
    do {                                                                                    \
        async_cp16(srcB0 + (size_t)(kt) * 128 + (h) * 524288,                               \
                   dstB0 + (nb) * 65536 + (h) * 16384);                                     \
        async_cp16(srcB0 + (size_t)(kt) * 128 + (h) * 524288 + 262144,                      \
                   dstB0 + (nb) * 65536 + (h) * 16384 + 8192);                              \
    } while (0)

    int rsw = (l15 & 7) << 4;
    int colh0 = (q * 16) ^ rsw;
    int colh1 = colh0 ^ 64;
    int arA = (wmw + l15) * 128;
    int arB = (wnw + l15) * 128;

    f32x4 acc[8][4];
#pragma unroll
    for (int a = 0; a < 8; ++a)
#pragma unroll
        for (int b = 0; b < 4; ++b) acc[a][b] = (f32x4){0.f, 0.f, 0.f, 0.f};

    STAGE_A(0, 0, 0);
    STAGE_A(0, 0, 1);
    STAGE_B(0, 0, 0);
    STAGE_B(0, 0, 1);
    STAGE_B(1, 1, 0);
    STAGE_B(1, 1, 1);
    asm volatile("s_waitcnt vmcnt(4)" ::: "memory");
    __builtin_amdgcn_s_barrier();
    asm volatile("" ::: "memory");

    int cur = 0;
    for (int t = 0; t < NTK; ++t, cur ^= 1) {
        const int nb = cur ^ 1;
        const char* pa = ldsc + (cur << 16);
        const char* pA0 = pa + arA;
        const char* pB0 = pa + 32768 + arB;

        if (t + 1 < NTK) {
            STAGE_A(nb, t + 1, 0);
            STAGE_A(nb, t + 1, 1);
        }

        short8 af[4][2], bf0[2][2], bf1[2][2];

#pragma unroll
        for (int tm = 0; tm < 4; ++tm) {
            af[tm][0] = *(const short8*)(pA0 + tm * 2048 + colh0);
            af[tm][1] = *(const short8*)(pA0 + tm * 2048 + colh1);
        }
#pragma unroll
        for (int tn = 0; tn < 2; ++tn) {
            bf0[tn][0] = *(const short8*)(pB0 + tn * 2048 + colh0);
            bf0[tn][1] = *(const short8*)(pB0 + tn * 2048 + colh1);
            bf1[tn][0] = *(const short8*)(pB0 + 4096 + tn * 2048 + colh0);
            bf1[tn][1] = *(const short8*)(pB0 + 4096 + tn * 2048 + colh1);
        }
        mfma_quad<0, 0>(acc, af, bf0);
        mfma_quad<0, 2>(acc, af, bf1);

        if (t + 2 < NTK) {
            asm volatile("s_waitcnt lgkmcnt(0)" ::: "memory");
            __builtin_amdgcn_s_barrier();
            asm volatile("" ::: "memory");
            STAGE_B(cur, t + 2, 0);
            STAGE_B(cur, t + 2, 1);
        }

#pragma unroll
        for (int tm = 0; tm < 4; ++tm) {
            af[tm][0] = *(const short8*)(pA0 + 8192 + tm * 2048 + colh0);
            af[tm][1] = *(const short8*)(pA0 + 8192 + tm * 2048 + colh1);
        }
        mfma_quad<4, 2>(acc, af, bf1);
        mfma_quad<4, 0>(acc, af, bf0);

        if (t + 2 < NTK) {
            asm volatile("s_waitcnt vmcnt(4) lgkmcnt(0)" ::: "memory");
            __builtin_amdgcn_s_barrier();
            asm volatile("" ::: "memory");
        } else if (t + 1 < NTK) {
            asm volatile("s_waitcnt vmcnt(0) lgkmcnt(0)" ::: "memory");
            __builtin_amdgcn_s_barrier();
            asm volatile("" ::: "memory");
        }
    }
#undef STAGE_A
#undef STAGE_B

#pragma unroll
    for (int a = 0; a < 8; ++a) {
        int mbase = m0g + wmw + (a >> 2) * 64 + (a & 3) * 16 + q * 4;
#pragma unroll
        for (int b = 0; b < 4; ++b) {
            int jj = j0g + wnw + (b >> 1) * 32 + (b & 1) * 16 + l15;
#pragma unroll
            for (int r = 0; r < 4; ++r) {
                size_t oidx = (size_t)(mbase + r) * JJ + jj;
                Out[oidx] = f2bf(acc[a][b][r]);
            }
        }
    }
}

// ---------------- K5/K6: per-node [192 x 192] @ [192 x 64] MFMA GEMM ----------------
// Rewritten: DMA double-buffered source staging (XOR-swizzled, like the GEMM),
// precomputed W_all for BRANCH 0 (coalesced 24.6 KB row load), float4 epilogue.
// LDS (dynamic 75008 B): lW[64*200] @0, lS[2][192*64] @25600, lBias @74752.
struct NodeFrags { short8 a[3][2], b[4][2]; };

__device__ __forceinline__ void node_stage(const unsigned short* src, char* dst, int tid) {
#pragma unroll
    for (int v = 0; v < 6; ++v) {
        int id = v * 256 + tid;              // 16-B chunk id in [0,1536)
        int m = id >> 3, c = id & 7;
        async_cp16((const char*)src + m * 128 + ((c * 16) ^ ((m & 7) << 4)),
                   dst + id * 16);
    }
}

__device__ __forceinline__ void node_read(const char* pS, const unsigned short* lW,
                                          int s, int wv, int q, int l15,
                                          int colh0, int colh1, NodeFrags& f) {
#pragma unroll
    for (int tm = 0; tm < 3; ++tm) {
        int rb = (wv * 48 + tm * 16 + l15) * 128;
        f.a[tm][0] = *(const short8*)(pS + rb + colh0);
        f.a[tm][1] = *(const short8*)(pS + rb + colh1);
    }
#pragma unroll
    for (int tn = 0; tn < 4; ++tn) {
        const unsigned short* wr = lW + (tn * 16 + l15) * 200 + s * 64 + q * 8;
        f.b[tn][0] = *(const short8*)wr;
        f.b[tn][1] = *(const short8*)(wr + 32);
    }
}

__device__ __forceinline__ void node_mfma(f32x4 (&acc)[3][4], const NodeFrags& f) {
#pragma unroll
    for (int h = 0; h < 2; ++h)
#pragma unroll
        for (int tm = 0; tm < 3; ++tm)
#pragma unroll
            for (int tn = 0; tn < 4; ++tn)
                acc[tm][tn] = __builtin_amdgcn_mfma_f32_16x16x32_bf16(
                    f.a[tm][h], f.b[tn][h], acc[tm][tn], 0, 0, 0);
}

template <int BRANCH>
__global__ __launch_bounds__(256) void k_node(const unsigned short* __restrict__ S0,
                                              const unsigned short* __restrict__ S1,
                                              const unsigned short* __restrict__ S2,
                                              const unsigned short* __restrict__ Wall,
                                              const float* __restrict__ E,
                                              const float* __restrict__ bias_pool,
                                              const float* __restrict__ mlp_w,
                                              const float* __restrict__ mlp_b,
                                              float* __restrict__ out) {
    extern __shared__ char lds[];
    unsigned short* lW = (unsigned short*)lds;            // 64*200 shorts
    char* lS0 = lds + 25600;                              // [2][192*64] shorts
    float* lBias = (float*)(lds + 74752);

    int n = blockIdx.x, tid = threadIdx.x, lane = tid & 63, wv = tid >> 6;
    int q = lane >> 4, l15 = lane & 15;
    int colh0 = (q * 16) ^ ((l15 & 7) << 4);
    int colh1 = colh0 ^ 64;

    const unsigned short* Ss0 = S0 + (size_t)n * JJ;
    const unsigned short* Ss1 = S1 + (size_t)n * JJ;
    const unsigned short* Ss2 = S2 + (size_t)n * JJ;

    // ---- lW + bias build ----
    if (BRANCH == 0) {
#pragma unroll
        for (int v = 0; v < 6; ++v) {
            int idx = v * 256 + tid;         // short8 id in [0,1536)
            int o = idx / 24, k8 = idx - o * 24;
            *(short8*)&lW[o * 200 + k8 * 8] =
                *(const short8*)&Wall[(size_t)n * 12288 + (size_t)idx * 8];
        }
        if (tid < 64) {
            float s = 0.f;
#pragma unroll
            for (int d = 0; d < ED; ++d) s += E[n * ED + d] * bias_pool[d * OO + tid];
            lBias[tid] = s;
        }
    } else {
        for (int idx = tid; idx < KC * OO; idx += 256) {
            int o = idx & 63, kap = idx >> 6;
            lW[o * 200 + kap] = f2bf(mlp_w[kap * OO + o]);
        }
        if (tid < 64) lBias[tid] = mlp_b[tid];
    }

    f32x4 acc[3][4];
#pragma unroll
    for (int a = 0; a < 3; ++a)
#pragma unroll
        for (int b = 0; b < 4; ++b) acc[a][b] = (f32x4){0.f, 0.f, 0.f, 0.f};

    // ---- prologue: DMA stages 0,1 ----
    node_stage(Ss0, lS0, tid);               // 6 cp16 -> buf0
    node_stage(Ss1, lS0 + 24576, tid);       // 6 cp16 -> buf1
    asm volatile("s_waitcnt vmcnt(6) lgkmcnt(0)" ::: "memory");   // buf0 + lW ready
    __builtin_amdgcn_s_barrier();
    asm volatile("" ::: "memory");

    NodeFrags f;
    // ---- s = 0 (buf0); then reuse buf0 for s=2 ----
    node_read(lS0, lW, 0, wv, q, l15, colh0, colh1, f);
    asm volatile("s_waitcnt lgkmcnt(0)" ::: "memory");   // all waves done reading buf0
    __builtin_amdgcn_s_barrier();
    asm volatile("" ::: "memory");
    node_stage(Ss2, lS0, tid);               // s=2 -> buf0 (6 cp16 in flight)
    node_mfma(acc, f);
    asm volatile("s_waitcnt vmcnt(6)" ::: "memory");     // s=1 landed
    __builtin_amdgcn_s_barrier();
    asm volatile("" ::: "memory");

    // ---- s = 1 (buf1) ----
    node_read(lS0 + 24576, lW, 1, wv, q, l15, colh0, colh1, f);
    node_mfma(acc, f);
    asm volatile("s_waitcnt vmcnt(0) lgkmcnt(0)" ::: "memory");   // s=2 landed
    __builtin_amdgcn_s_barrier();
    asm volatile("" ::: "memory");

    // ---- s = 2 (buf0) ----
    node_read(lS0, lW, 2, wv, q, l15, colh0, colh1, f);
    node_mfma(acc, f);

    // ---- epilogue: float4 stores (4 t-contiguous per acc reg, same b) ----
#pragma unroll
    for (int tm = 0; tm < 3; ++tm) {
#pragma unroll
        for (int tn = 0; tn < 4; ++tn) {
            int o = tn * 16 + l15;
            int m0 = wv * 48 + tm * 16 + q * 4;
            int b = m0 / TT, t0 = m0 - b * TT;
            float bias = lBias[o];
            float4 vv;
            vv.x = acc[tm][tn][0] + bias;
            vv.y = acc[tm][tn][1] + bias;
            vv.z = acc[tm][tn][2] + bias;
            vv.w = acc[tm][tn][3] + bias;
            *(float4*)&out[(((size_t)b * OO + o) * NN + n) * TT + t0] = vv;
        }
    }
}

// ---------------- launch ----------------
extern "C" void kernel_launch(void* const* d_in, const int* in_sizes, int n_in,
                              void* d_out, int out_size, void* d_ws, size_t ws_size,
                              hipStream_t stream) {
    const float* x         = (const float*)d_in[0];
    const float* node_emb  = (const float*)d_in[1];
    const float* support   = (const float*)d_in[2];
    const float* wpool     = (const float*)d_in[3];
    const float* bpool     = (const float*)d_in[4];
    const float* mlp_w     = (const float*)d_in[5];
    const float* mlp_b     = (const float*)d_in[6];
    float* out             = (float*)d_out;

    unsigned short* Abf = (unsigned short*)d_ws;                 // A (adaptive) bf16
    unsigned short* Atb = Abf + (size_t)NN * NN;                 // support^T bf16
    unsigned short* b1  = Atb + (size_t)NN * NN;
    unsigned short* b2  = b1 + (size_t)NJ;
    unsigned short* b3  = b2 + (size_t)NJ;
    unsigned short* b4  = b3 + (size_t)NJ;
    unsigned short* b5  = b4 + (size_t)NJ;
    // liveness (diffusion branch FIRST so b3 is free for W_all at node0):
    //   make : X2->b2, X2t->b1
    //   G13  : Y1->b4, Z1->b5          (B = X2t = b1; X2t dead after)
    //   T2   : b5 -> b3 (Z1t)
    //   G4   : Z2 = At*Z1t -> b1
    //   node1: (b2, b5, b1) -> out+NJ  (Z1, Z2 dead after)
    //   T1   : b4 -> b3 (Y1t)
    //   G2   : Y2' = A*Y1t -> b5       (weight-folded: no Csub)
    //   wfold: W_all -> b3             (Y1t dead)
    //   node0: (b2, b4, b5) + W_all@b3 -> out

    static int attr_done = 0;
    if (!attr_done) {
        hipFuncSetAttribute(reinterpret_cast<const void*>(k_gemm8<0>),
                            hipFuncAttributeMaxDynamicSharedMemorySize, 131072);
        hipFuncSetAttribute(reinterpret_cast<const void*>(k_gemm8<1>),
                            hipFuncAttributeMaxDynamicSharedMemorySize, 131072);
        hipFuncSetAttribute(reinterpret_cast<const void*>(k_gemm8<2>),
                            hipFuncAttributeMaxDynamicSharedMemorySize, 131072);
        hipFuncSetAttribute(reinterpret_cast<const void*>(k_make_X2b),
                            hipFuncAttributeMaxDynamicSharedMemorySize, 106752);
        hipFuncSetAttribute(reinterpret_cast<const void*>(k_node<0>),
                            hipFuncAttributeMaxDynamicSharedMemorySize, 75008);
        hipFuncSetAttribute(reinterpret_cast<const void*>(k_node<1>),
                            hipFuncAttributeMaxDynamicSharedMemorySize, 75008);
        attr_done = 1;
    }

    dim3 gg13(48, 8, 2);             // merged Y1/Z1: 768 blocks = 3 exact rounds
    dim3 gg1(48, 8, 1);
    dim3 gt(192, 32);

    // prep
    k_softmax_A<<<NN, 256, 0, stream>>>(node_emb, Abf);
    k_trans_bf<<<dim3(64, 64), dim3(32, 8), 0, stream>>>(support, Atb);
    k_make_X2b<<<dim3(16, 64), 256, 106752, stream>>>(x, b2, b1);

    // merged: Y1 = A*X2 (z=0), Z1 = At*X2 (z=1)
    k_gemm8<0><<<gg13, 512, 131072, stream>>>(Abf, Atb, b1, b4, b5);

    // diffusion branch first
    k_trans16<<<gt, 256, 0, stream>>>(b5, b3);                       // Z1t
    k_gemm8<1><<<gg1, 512, 131072, stream>>>(Atb, Atb, b3, b1, b1);  // Z2 -> b1
    k_node<1><<<NN, 256, 75008, stream>>>(b2, b5, b1, b2, node_emb, bpool, mlp_w, mlp_b,
                                          out + (size_t)NJ);

    // adaptive branch
    k_trans16<<<gt, 256, 0, stream>>>(b4, b3);                       // Y1t
    k_gemm8<2><<<gg1, 512, 131072, stream>>>(Abf, Abf, b3, b5, b5);  // Y2' -> b5
    k_wfold<<<dim3(48, 8), 256, 0, stream>>>(node_emb, wpool, b3);   // W_all -> b3
    k_node<0><<<NN, 256, 75008, stream>>>(b2, b4, b5, b3, node_emb, bpool, mlp_w, mlp_b,
                                          out);
}